// Round 7
// baseline (534.151 us; speedup 1.0000x reference)
//
#include <hip/hip_runtime.h>

// ---------------------------------------------------------------------------
// TransformerBlock on MI355X (gfx950) — round 7.
// Token-major: t = s*B + b, x is (8192, 1024).
// GEMMs: m97-style global_load_lds staging + L2-locality grid swizzle.
// Attention v7: wave-specialized (4 S-waves + 4 PV-waves, 512 thr) with
// DETERMINISTIC balance: 256 blocks, block j does item0 (qt=j, half0,
// j+1 chunks) then item1 (qt=31-j, half1, 32-j chunks) = exactly 33 chunks
// per block -> no dispatch lottery. PV waves double-buffer V^T frags in
// registers. Double-buffered Ks (stride 520) / Ps; one barrier per chunk.
// ws slots (MiB): S0[0,16) h/vt/m; S1[16,32) q/ctx; S2[32,48) k/g.lo;
// S3[48,64) vtmp/l/g.hi; [64,80) bf16 weights. d_out = attn partial scratch.
// ---------------------------------------------------------------------------

typedef __bf16 bf16;
typedef bf16 bf16x8 __attribute__((ext_vector_type(8)));
typedef bf16 bf16x4 __attribute__((ext_vector_type(4)));
typedef float f32x4 __attribute__((ext_vector_type(4)));

#define MFMA16x16x32(A, B, C) __builtin_amdgcn_mfma_f32_16x16x32_bf16(A, B, C, 0, 0, 0)

__device__ __forceinline__ void gload16(const void* g, void* l) {
  __builtin_amdgcn_global_load_lds(
      (const __attribute__((address_space(1))) void*)g,
      (__attribute__((address_space(3))) void*)l, 16, 0, 0);
}

// ---------------- f32 -> bf16 weight conversion ----------------------------
__global__ __launch_bounds__(256) void wcvt(
    const float* __restrict__ src, bf16* __restrict__ dst, int n)
{
  const int i = (blockIdx.x * 256 + threadIdx.x) * 4;
  if (i < n) {
    const float4 v = *(const float4*)(src + i);
    bf16x4 o;
    o[0] = (bf16)v.x; o[1] = (bf16)v.y; o[2] = (bf16)v.z; o[3] = (bf16)v.w;
    *(bf16x4*)(dst + i) = o;
  }
}

// ---------------- RMSNorm: (8192 x 1024) f32 -> bf16 -----------------------
__global__ __launch_bounds__(256) void rmsnorm_kernel(
    const float* __restrict__ x, const float* __restrict__ w, bf16* __restrict__ out)
{
  const int row = blockIdx.x;
  const int tid = threadIdx.x;
  const float4 v = *(const float4*)(x + (size_t)row * 1024 + tid * 4);
  float ss = v.x * v.x + v.y * v.y + v.z * v.z + v.w * v.w;
#pragma unroll
  for (int off = 1; off < 64; off <<= 1) ss += __shfl_xor(ss, off, 64);
  __shared__ float red[4];
  if ((tid & 63) == 0) red[tid >> 6] = ss;
  __syncthreads();
  const float tot = red[0] + red[1] + red[2] + red[3];
  const float inv = rsqrtf(tot * (1.0f / 1024.0f) + 1e-8f);
  const float4 g = *(const float4*)(w + tid * 4);
  bf16x4 o;
  o[0] = (bf16)(v.x * g.x * inv);
  o[1] = (bf16)(v.y * g.y * inv);
  o[2] = (bf16)(v.z * g.z * inv);
  o[3] = (bf16)(v.w * g.w * inv);
  *(bf16x4*)(out + (size_t)row * 1024 + tid * 4) = o;
}

// ---------------- GEMM: C = A * W^T + bias, swizzled 1-D grid --------------
enum { EPI_BF16 = 0, EPI_RES = 1, EPI_GELU = 2, EPI_QKV = 3 };

template <int EPI>
__global__ __launch_bounds__(256, 3) void gemm_bt2(
    const bf16* __restrict__ A,   // M x K
    const bf16* __restrict__ B,   // N x K
    const float* __restrict__ bias,
    const float* res,             // may alias outF
    float* outF, bf16* outQ, bf16* outK, bf16* outV,
    int M, int N, int K)
{
  __shared__ bf16 As[128 * 32];
  __shared__ bf16 Bs[128 * 32];
  const int tid = threadIdx.x;
  // super-rows of 16 bm: concurrent blocks share a 4 MB A-slice (L2-resident)
  const int Nb = N >> 7;
  const int lin = blockIdx.x;
  const int sup = lin / (Nb << 4);
  const int rem = lin - sup * (Nb << 4);
  const int bm = (sup << 4) + (rem & 15);
  const int bn = rem >> 4;
  const int w = tid >> 6, lane = tid & 63;
  const int q = lane >> 4, lr = lane & 15;
  const int wr = (w >> 1) * 64, wc = (w & 1) * 64;
  f32x4 acc[4][4] = {};
  const int srow = lane >> 2;
  const int gch = ((lane & 3) - ((lane >> 3) & 3)) & 3;
  const bf16* Ab = A + (size_t)(bm * 128) * K;
  const bf16* Bb = B + (size_t)(bn * 128) * K;
  const int sw = ((q + (lr >> 1)) & 3) * 16;

  for (int k0 = 0; k0 < K; k0 += 32) {
    __syncthreads();
#pragma unroll
    for (int c = 0; c < 2; c++) {
      const int r = (w * 2 + c) * 16 + srow;
      gload16(Ab + (size_t)r * K + k0 + gch * 8, &As[(w * 2 + c) * 512]);
      gload16(Bb + (size_t)r * K + k0 + gch * 8, &Bs[(w * 2 + c) * 512]);
    }
    __syncthreads();
    bf16x8 af[4], bfr[4];
#pragma unroll
    for (int mt = 0; mt < 4; mt++)
      af[mt] = *(const bf16x8*)((const char*)As + (wr + mt * 16 + lr) * 64 + sw);
#pragma unroll
    for (int nt = 0; nt < 4; nt++)
      bfr[nt] = *(const bf16x8*)((const char*)Bs + (wc + nt * 16 + lr) * 64 + sw);
#pragma unroll
    for (int mt = 0; mt < 4; mt++)
#pragma unroll
      for (int nt = 0; nt < 4; nt++)
        acc[mt][nt] = MFMA16x16x32(af[mt], bfr[nt], acc[mt][nt]);
  }
  const int gm0 = bm * 128 + wr + q * 4;
  const int gn0 = bn * 128 + wc + lr;
  bf16* outs = nullptr;
  if constexpr (EPI == EPI_QKV) {
    const int reg = (bn * 128) >> 10;
    outs = reg == 0 ? outQ : (reg == 1 ? outK : outV);
  } else {
    outs = outQ;
  }
#pragma unroll
  for (int nt = 0; nt < 4; nt++) {
    const int gn = gn0 + nt * 16;
    const float bv = bias[gn];
#pragma unroll
    for (int mt = 0; mt < 4; mt++) {
#pragma unroll
      for (int r = 0; r < 4; r++) {
        float v = acc[mt][nt][r] + bv;
        const int gm = gm0 + mt * 16 + r;
        if constexpr (EPI == EPI_GELU) {
          v = 0.5f * v * (1.0f + erff(v * 0.70710678118654752f));
          outs[(size_t)gm * N + gn] = (bf16)v;
        } else if constexpr (EPI == EPI_BF16) {
          outs[(size_t)gm * N + gn] = (bf16)v;
        } else if constexpr (EPI == EPI_QKV) {
          outs[(size_t)gm * 1024 + (gn & 1023)] = (bf16)v;
        } else {
          const size_t idx = (size_t)gm * N + gn;
          outF[idx] = v + res[idx];
        }
      }
    }
  }
}

// ---------------- V transpose: vtmp (t,n) -> vt[bh][dim][key] --------------
__global__ __launch_bounds__(256) void vtrans_kernel(
    const bf16* __restrict__ vtmp, bf16* __restrict__ vt)
{
  __shared__ bf16 tile[64 * 72];
  const int kt = blockIdx.x;
  const int dt = blockIdx.y;
  const int bh = blockIdx.z;
  const int b = bh >> 1, h = bh & 1;
  const int tid = threadIdx.x;
#pragma unroll
  for (int it = 0; it < 2; it++) {
    const int key = it * 32 + (tid >> 3);
    const int dc = (tid & 7) * 8;
    const bf16x8 v = *(const bf16x8*)(vtmp +
        (size_t)((kt * 64 + key) * 4 + b) * 1024 + h * 512 + dt * 64 + dc);
    *(bf16x8*)&tile[key * 72 + dc] = v;
  }
  __syncthreads();
#pragma unroll
  for (int it = 0; it < 2; it++) {
    const int dim = it * 32 + (tid >> 3);
    const int kc = (tid & 7) * 8;
    bf16x8 o;
#pragma unroll
    for (int j = 0; j < 8; j++) o[j] = tile[(kc + j) * 72 + dim];
    *(bf16x8*)(vt + (size_t)bh * (1u << 20) +
               (size_t)(dt * 64 + dim) * 2048 + kt * 64 + kc) = o;
  }
}

// ---------------- Attention v7: wave-specialized, balanced -----------------
// 512 threads: waves 0-3 S (QK^T+exp+K staging), 4-7 PV (O accum, P x V^T).
// Block j (of 32 per bh): item0 = (qt=j, half0), item1 = (qt=31-j, half1)
// -> 33 chunks per block, deterministic. One barrier per chunk. PV V^T
// frags register-double-buffered.
__global__ __launch_bounds__(512, 1) void attn_kernel(
    const bf16* __restrict__ qb, const bf16* __restrict__ kb,
    const bf16* __restrict__ vtg, bf16* __restrict__ opart,
    float* __restrict__ lpart)
{
  __shared__ bf16 Ks[2][32 * 520];   // 2 x 33280 B
  __shared__ bf16 Ps[2][4][16 * 40]; // 2 x  5120 B  (76800 total)
  const int bh = blockIdx.x;          // 0..7 -> XCD affinity
  const int j = blockIdx.y;           // 0..31
  const int b = bh >> 1, h = bh & 1;
  const int tid = threadIdx.x;
  const int w = tid >> 6, lane = tid & 63;
  const int q = lane >> 4, lr = lane & 15;
  const float sc = 0.044194173824159216f;  // 1/sqrt(512)

  for (int item = 0; item < 2; item++) {
    const int half = item;
    const int qt = item ? (31 - j) : j;
    const int qrow0 = qt * 64;
    const int c0 = item ? (qt + 1) : 0;
    const int c1 = c0 + (qt + 1);

    if (w < 4) {
      // ================= S-waves =================
      bf16x8 Qf[16];
      {
        const bf16* qp = qb + (size_t)((qrow0 + w * 16 + lr) * 4 + b) * 1024 + h * 512 + q * 8;
#pragma unroll
        for (int kk = 0; kk < 16; kk++) Qf[kk] = *(const bf16x8*)(qp + kk * 32);
      }
      const bf16* krow0 = kb + (size_t)b * 1024 + h * 512 + lane * 8;  // per-lane 16B
      // stage K[c0]
#pragma unroll
      for (int jj = 0; jj < 8; jj++)
        gload16(krow0 + (size_t)((c0 * 32 + w * 8 + jj) * 4) * 1024,
                &Ks[c0 & 1][(w * 8 + jj) * 520]);
      __syncthreads();  // [B0] K[c0] visible
      const int myrow = qrow0 + w * 16 + q * 4;
      for (int t = c0; t <= c1; t++) {
        if (t < c1) {
          const int p = t & 1;
          const int kc = t * 32;
          // prefetch K[t+1] first — drained by this iter's end barrier
          if (t + 1 < c1) {
            const int kc2 = (t + 1) * 32;
#pragma unroll
            for (int jj = 0; jj < 8; jj++)
              gload16(krow0 + (size_t)((kc2 + w * 8 + jj) * 4) * 1024,
                      &Ks[1 - p][(w * 8 + jj) * 520]);
          }
          const bool deadc = kc > qrow0 + w * 16 + 15;
          float p0[4], p1[4];
          if (!deadc) {
            f32x4 S0 = {}, S1 = {};
#pragma unroll
            for (int kk = 0; kk < 16; kk++) {
              const bf16x8 k0 = *(const bf16x8*)&Ks[p][lr * 520 + kk * 32 + q * 8];
              const bf16x8 k1 = *(const bf16x8*)&Ks[p][(16 + lr) * 520 + kk * 32 + q * 8];
              S0 = MFMA16x16x32(Qf[kk], k0, S0);
              S1 = MFMA16x16x32(Qf[kk], k1, S1);
            }
#pragma unroll
            for (int r = 0; r < 4; r++) {
              const int row = myrow + r;
              p0[r] = (kc + lr > row) ? 0.f : __expf(S0[r] * sc);
              p1[r] = (kc + 16 + lr > row) ? 0.f : __expf(S1[r] * sc);
            }
          } else {
#pragma unroll
            for (int r = 0; r < 4; r++) { p0[r] = 0.f; p1[r] = 0.f; }
          }
#pragma unroll
          for (int r = 0; r < 4; r++) {
            Ps[p][w][(q * 4 + r) * 40 + lr] = (bf16)p0[r];
            Ps[p][w][(q * 4 + r) * 40 + 16 + lr] = (bf16)p1[r];
          }
        }
        __syncthreads();  // [Bt] P[t] visible; K[t+1] landed; P[t-1] reads done
      }
    } else {
      // ================= PV-waves =================
      const int pw = w - 4;
      f32x4 O[4][8] = {};
      f32x4 lac = {};
      bf16x8 ones;
#pragma unroll
      for (int e = 0; e < 8; e++) ones[e] = (bf16)1.0f;
      const bf16* vbase = vtg + ((size_t)bh << 20) + (size_t)(pw * 128 + lr) * 2048 + q * 8;
      // register-double-buffered V^T frags: vf[(c-c0)&1] holds chunk c
      bf16x8 vf[2][8];
#pragma unroll
      for (int ct = 0; ct < 8; ct++)
        vf[0][ct] = *(const bf16x8*)(vbase + (size_t)(ct * 16) * 2048 + c0 * 32);
      __syncthreads();  // [B0]
      for (int t = c0; t <= c1; t++) {
        // issue next chunk's V loads before consuming (chunk t, used at t+1)
        if (t > c0 && t < c1) {
          const int nb = (t - c0) & 1;
#pragma unroll
          for (int ct = 0; ct < 8; ct++)
            vf[nb][ct] = *(const bf16x8*)(vbase + (size_t)(ct * 16) * 2048 + t * 32);
        }
        if (t > c0) {
          const int p = (t - 1) & 1;
          const int cb = (t - 1 - c0) & 1;
          bf16x8 pa[4];
#pragma unroll
          for (int rt = 0; rt < 4; rt++)
            pa[rt] = *(const bf16x8*)&Ps[p][rt][lr * 40 + q * 8];
          lac = MFMA16x16x32(pa[pw], ones, lac);
#pragma unroll
          for (int ct = 0; ct < 8; ct++)
#pragma unroll
            for (int rt = 0; rt < 4; rt++)
              O[rt][ct] = MFMA16x16x32(pa[rt], vf[cb][ct], O[rt][ct]);
        }
        __syncthreads();  // [Bt]
      }
      // ---- write partials: opart[half][bh][row 2048][dim 512] (= d_out) ----
      bf16* op = opart + (size_t)half * (8u << 20) + (size_t)bh * (1u << 20);
#pragma unroll
      for (int rt = 0; rt < 4; rt++)
#pragma unroll
        for (int ct = 0; ct < 8; ct++)
#pragma unroll
          for (int r = 0; r < 4; r++)
            op[(size_t)(qrow0 + rt * 16 + q * 4 + r) * 512 + pw * 128 + ct * 16 + lr] =
                (bf16)O[rt][ct][r];
      if (lr == 0) {
#pragma unroll
        for (int r = 0; r < 4; r++)
          lpart[half * 16384 + bh * 2048 + qrow0 + pw * 16 + q * 4 + r] = lac[r];
      }
    }
  }
}

// ---------------- combine: ctx = (O0+O1)/(l0+l1), bf16 token-major ---------
__global__ __launch_bounds__(256) void attn_combine(
    const bf16* __restrict__ opart, const float* __restrict__ lpart,
    bf16* __restrict__ ctx)
{
  const int gid = blockIdx.x * 256 + threadIdx.x;
  const int bh = gid >> 17;
  const int rem = gid & 131071;
  const int row = rem >> 6;
  const int dc = (rem & 63) * 8;
  const size_t o = (size_t)bh * (1u << 20) + (size_t)row * 512 + dc;
  const bf16x8 a = *(const bf16x8*)(opart + o);
  const bf16x8 c = *(const bf16x8*)(opart + (size_t)(8u << 20) + o);
  const float inv = 1.0f /
      (lpart[bh * 2048 + row] + lpart[16384 + bh * 2048 + row]);
  bf16x8 ov;
#pragma unroll
  for (int e = 0; e < 8; e++) ov[e] = (bf16)(((float)a[e] + (float)c[e]) * inv);
  const int b = bh >> 1, h = bh & 1;
  *(bf16x8*)(ctx + (size_t)(row * 4 + b) * 1024 + h * 512 + dc) = ov;
}

// ---------------------------------------------------------------------------
extern "C" void kernel_launch(void* const* d_in, const int* in_sizes, int n_in,
                              void* d_out, int out_size, void* d_ws, size_t ws_size,
                              hipStream_t stream)
{
  (void)in_sizes; (void)n_in; (void)out_size; (void)ws_size;
  const float* x    = (const float*)d_in[0];
  const float* wn1  = (const float*)d_in[1];
  const float* wqkv = (const float*)d_in[2];
  const float* bqkv = (const float*)d_in[3];
  const float* wout = (const float*)d_in[4];
  const float* bout = (const float*)d_in[5];
  const float* wn2  = (const float*)d_in[6];
  const float* W1   = (const float*)d_in[7];
  const float* b1   = (const float*)d_in[8];
  const float* W2   = (const float*)d_in[9];
  const float* b2   = (const float*)d_in[10];
  float* out = (float*)d_out;

  char* ws = (char*)d_ws;
  const size_t Mi = 1u << 20;
  bf16* S0v = (bf16*)(ws);              // h -> vt -> m
  bf16* S1v = (bf16*)(ws + 16 * Mi);    // q -> ctx
  bf16* S2v = (bf16*)(ws + 32 * Mi);    // k -> g (lower half)
  bf16* S3v = (bf16*)(ws + 48 * Mi);    // vtmp -> l -> g (upper half)
  bf16* wqb = (bf16*)(ws + 64 * Mi);
  bf16* wob = (bf16*)(ws + 70 * Mi);
  bf16* w1b = (bf16*)(ws + 72 * Mi);
  bf16* w2b = (bf16*)(ws + 76 * Mi);
  const int M = 8192;

  wcvt<<<3072, 256, 0, stream>>>(wqkv, wqb, 3145728);
  wcvt<<<1024, 256, 0, stream>>>(wout, wob, 1048576);
  wcvt<<<2048, 256, 0, stream>>>(W1, w1b, 2097152);
  wcvt<<<2048, 256, 0, stream>>>(W2, w2b, 2097152);
  rmsnorm_kernel<<<8192, 256, 0, stream>>>(x, wn1, S0v);
  gemm_bt2<EPI_QKV><<<64 * 24, 256, 0, stream>>>(
      S0v, wqb, bqkv, nullptr, nullptr, S1v, S2v, S3v, M, 3072, 1024);
  vtrans_kernel<<<dim3(32, 8, 8), 256, 0, stream>>>(S3v, S0v);
  attn_kernel<<<dim3(8, 32), 512, 0, stream>>>(
      S1v, S2v, S0v, (bf16*)d_out, (float*)S3v);
  attn_combine<<<4096, 256, 0, stream>>>((const bf16*)d_out, (const float*)S3v, S1v);
  gemm_bt2<EPI_RES><<<64 * 8, 256, 0, stream>>>(
      S1v, wob, bout, x, out, nullptr, nullptr, nullptr, M, 1024, 1024);
  rmsnorm_kernel<<<8192, 256, 0, stream>>>(out, wn2, S0v);
  gemm_bt2<EPI_GELU><<<64 * 16, 256, 0, stream>>>(
      S0v, w1b, b1, nullptr, nullptr, S2v, nullptr, nullptr, M, 2048, 1024);
  gemm_bt2<EPI_RES><<<64 * 8, 256, 0, stream>>>(
      S2v, w2b, b2, out, out, nullptr, nullptr, nullptr, M, 1024, 2048);
}